// Round 5
// baseline (534.732 us; speedup 1.0000x reference)
//
#include <hip/hip_runtime.h>

constexpr int IN_C   = 3;
constexpr int OUT_C  = 64;
constexpr int NB     = 27;
constexpr int WROW   = 84;               // 81 padded to 84 (16B-aligned rows)
constexpr int WFOLDT = OUT_C * WROW;     // 5376
constexpr int CR     = 1024;             // clusters per range-block (16 KB LDS bins)

typedef float f32x4 __attribute__((ext_vector_type(4)));

// ---- stage A+P fused: cluster-range LDS binning, zero global atomics ----
// Block b owns clusters [b*CR, b*CR+CR). It streams the whole cluster[] array
// (uint4), LDS-accumulates in-range points, then writes pooled means directly.
__global__ __launch_bounds__(512) void
k_poolscan(const int* __restrict__ cluster, const float* __restrict__ x,
           float4* __restrict__ pooled, int N, int K) {
    __shared__ float bins[CR * 4];       // sx, sy, sz, cnt per cluster
    const int tid = threadIdx.x;
    const unsigned base = (unsigned)blockIdx.x * CR;

    for (int i = tid; i < CR * 4; i += blockDim.x) bins[i] = 0.f;
    __syncthreads();

    const int N4 = N >> 2;
    const uint4* __restrict__ cl4 = reinterpret_cast<const uint4*>(cluster);
    for (int i = tid; i < N4; i += blockDim.x) {
        uint4 c = cl4[i];
        int n = i * 4;
        unsigned r;
        r = c.x - base;
        if (r < CR) {
            atomicAdd(&bins[r * 4 + 0], x[3 * (n + 0) + 0]);
            atomicAdd(&bins[r * 4 + 1], x[3 * (n + 0) + 1]);
            atomicAdd(&bins[r * 4 + 2], x[3 * (n + 0) + 2]);
            atomicAdd(&bins[r * 4 + 3], 1.0f);
        }
        r = c.y - base;
        if (r < CR) {
            atomicAdd(&bins[r * 4 + 0], x[3 * (n + 1) + 0]);
            atomicAdd(&bins[r * 4 + 1], x[3 * (n + 1) + 1]);
            atomicAdd(&bins[r * 4 + 2], x[3 * (n + 1) + 2]);
            atomicAdd(&bins[r * 4 + 3], 1.0f);
        }
        r = c.z - base;
        if (r < CR) {
            atomicAdd(&bins[r * 4 + 0], x[3 * (n + 2) + 0]);
            atomicAdd(&bins[r * 4 + 1], x[3 * (n + 2) + 1]);
            atomicAdd(&bins[r * 4 + 2], x[3 * (n + 2) + 2]);
            atomicAdd(&bins[r * 4 + 3], 1.0f);
        }
        r = c.w - base;
        if (r < CR) {
            atomicAdd(&bins[r * 4 + 0], x[3 * (n + 3) + 0]);
            atomicAdd(&bins[r * 4 + 1], x[3 * (n + 3) + 1]);
            atomicAdd(&bins[r * 4 + 2], x[3 * (n + 3) + 2]);
            atomicAdd(&bins[r * 4 + 3], 1.0f);
        }
    }
    // scalar tail
    for (int n = N4 * 4 + tid; n < N; n += blockDim.x) {
        unsigned r = (unsigned)cluster[n] - base;
        if (r < CR) {
            atomicAdd(&bins[r * 4 + 0], x[3 * n + 0]);
            atomicAdd(&bins[r * 4 + 1], x[3 * n + 1]);
            atomicAdd(&bins[r * 4 + 2], x[3 * n + 2]);
            atomicAdd(&bins[r * 4 + 3], 1.0f);
        }
    }
    __syncthreads();

    // flush: mean, coalesced plain stores
    for (int i = tid; i < CR; i += blockDim.x) {
        unsigned k = base + i;
        if (k < (unsigned)K) {
            float cnt = bins[i * 4 + 3];
            float inv = 1.0f / fmaxf(cnt, 1.0f);
            pooled[k] = make_float4(bins[i * 4 + 0] * inv,
                                    bins[i * 4 + 1] * inv,
                                    bins[i * 4 + 2] * inv, 0.f);
        }
    }
    if (blockIdx.x == 0 && tid == 0)
        pooled[K] = make_float4(0.f, 0.f, 0.f, 0.f);   // sentinel row
}

// ---- stage B: fold W_conv with W_lin[3:,:], TRANSPOSED: WcT[j*84 + (o*3+i)] ----
__global__ void k_fold(const float* __restrict__ Wc, const float* __restrict__ Wl,
                       float* __restrict__ WcT) {
    int t = blockIdx.x * blockDim.x + threadIdx.x;
    if (t >= WFOLDT) return;
    int j = t / WROW;
    int f = t % WROW;     // f = o*3+i
    float acc = 0.f;
    if (f < NB * IN_C) {
        #pragma unroll
        for (int j2 = 0; j2 < OUT_C; ++j2)
            acc = fmaf(Wc[f * 64 + j2], Wl[(IN_C + j2) * OUT_C + j], acc);
    }
    WcT[t] = acc;
}

// ---- stage C: cluster-parallel. lane = cluster, loop over 64 channels. ----
__global__ __launch_bounds__(256) void
k_conv(const int* __restrict__ nb, const float4* __restrict__ pooled4,
       const float* __restrict__ WcT, const float* __restrict__ b_lin,
       float* __restrict__ v, int K) {
    __shared__ float xpose[4 * 64 * 17];     // 17408 B, per-wave slices
    const int lane = threadIdx.x & 63;
    const int wv   = threadIdx.x >> 6;
    const int wid  = (blockIdx.x * blockDim.x + threadIdx.x) >> 6;
    const int base = wid * 64;
    if (base >= K) return;
    const int kme = min(base + lane, K - 1);

    const int* nbrow = nb + (size_t)kme * NB;
    const unsigned uK = (unsigned)K;

    // 27 per-lane gathers; -1 maps (unsigned min) to zero sentinel row at K
    float4 p[NB];
    #pragma unroll
    for (int o = 0; o < NB; ++o) {
        unsigned s = min((unsigned)nbrow[o], uK);
        p[o] = pooled4[s];
    }

    float* xb = xpose + wv * (64 * 17);
    const int c4 = lane >> 4, jloc = lane & 15;

    #pragma unroll 1
    for (int jb = 0; jb < 4; ++jb) {
        #pragma unroll 2
        for (int jl = 0; jl < 16; ++jl) {
            const int j = jb * 16 + jl;
            const float* __restrict__ wj = WcT + j * WROW;   // wave-uniform row
            float a0 = b_lin[j], a1 = 0.f, a2 = 0.f;
            #pragma unroll
            for (int o = 0; o < NB; ++o) {
                a0 = fmaf(p[o].x, wj[o * 3 + 0], a0);
                a1 = fmaf(p[o].y, wj[o * 3 + 1], a1);
                a2 = fmaf(p[o].z, wj[o * 3 + 2], a2);
            }
            xb[lane * 17 + jl] = a0 + a1 + a2;               // 2-way banks: free
        }
        // transpose store: 16 coalesced 256B store instrs per jb
        #pragma unroll
        for (int cg = 0; cg < 16; ++cg) {
            int cl = cg * 4 + c4;
            int kk = base + cl;
            if (kk < K)
                v[(size_t)kk * OUT_C + jb * 16 + jloc] = xb[cl * 17 + jloc];
        }
    }
}

// ---- stage D: u[n] = x[n] @ W_lin[0:3] + v[cluster[n]] ; 4 pts/wave, float4 IO ----
__global__ void k_point(const float* __restrict__ x, const int* __restrict__ cluster,
                        const float* __restrict__ v, const float* __restrict__ Wl,
                        float* __restrict__ out, int N) {
    int lane = threadIdx.x & 63;
    int sub  = lane >> 4;
    int jj   = (lane & 15) * 4;
    int gwid   = (blockIdx.x * blockDim.x + threadIdx.x) >> 6;
    int nwaves = (gridDim.x * blockDim.x) >> 6;

    float4 w0 = *reinterpret_cast<const float4*>(Wl + 0 * OUT_C + jj);
    float4 w1 = *reinterpret_cast<const float4*>(Wl + 1 * OUT_C + jj);
    float4 w2 = *reinterpret_cast<const float4*>(Wl + 2 * OUT_C + jj);

    for (int base = gwid * 4; base < N; base += nwaves * 4) {
        int n = base + sub;
        if (n < N) {
            int c  = cluster[n];
            float x0 = x[n * 3 + 0];
            float x1 = x[n * 3 + 1];
            float x2 = x[n * 3 + 2];
            float4 acc = *reinterpret_cast<const float4*>(v + (size_t)c * OUT_C + jj);
            acc.x = fmaf(x0, w0.x, fmaf(x1, w1.x, fmaf(x2, w2.x, acc.x)));
            acc.y = fmaf(x0, w0.y, fmaf(x1, w1.y, fmaf(x2, w2.y, acc.y)));
            acc.z = fmaf(x0, w0.z, fmaf(x1, w1.z, fmaf(x2, w2.z, acc.z)));
            acc.w = fmaf(x0, w0.w, fmaf(x1, w1.w, fmaf(x2, w2.w, acc.w)));
            // nontemporal: don't let the 256MB output evict v from L2/L3
            f32x4 av = {acc.x, acc.y, acc.z, acc.w};
            __builtin_nontemporal_store(av,
                reinterpret_cast<f32x4*>(out + (size_t)n * OUT_C + jj));
        }
    }
}

extern "C" void kernel_launch(void* const* d_in, const int* in_sizes, int n_in,
                              void* d_out, int out_size, void* d_ws, size_t ws_size,
                              hipStream_t stream) {
    const float* x      = (const float*)d_in[0];
    const int*   cluster= (const int*)  d_in[1];
    const int*   nb     = (const int*)  d_in[2];
    const float* W_conv = (const float*)d_in[3];
    const float* W_lin  = (const float*)d_in[4];
    const float* b_lin  = (const float*)d_in[5];
    float* out = (float*)d_out;

    const int N = in_sizes[1];         // 1,000,000
    const int K = in_sizes[2] / NB;    // 200,000

    // workspace layout
    char* ws = (char*)d_ws;
    float4* pooled4 = (float4*)ws;                     // (K+1) * 16 B (sentinel at K)
    size_t off = (size_t)(K + 1) * sizeof(float4);
    off = ((off + 255) / 256) * 256;
    float* WcT = (float*)(ws + off);                   // 21504 B
    off += ((WFOLDT * sizeof(float) + 255) / 256) * 256;
    float* v = (float*)(ws + off);                     // K * 64 * 4 B (51.2 MB)

    k_fold <<<(WFOLDT + 255) / 256, 256, 0, stream>>>(W_conv, W_lin, WcT);

    int R = (K + CR - 1) / CR;                         // 196 range-blocks
    k_poolscan<<<R, 512, 0, stream>>>(cluster, x, pooled4, N, K);

    int conv_waves  = (K + 63) / 64;                   // 3125
    int conv_blocks = (conv_waves + 3) / 4;            // 782
    k_conv <<<conv_blocks, 256, 0, stream>>>(nb, pooled4, WcT, b_lin, v, K);

    k_point<<<2048, 256, 0, stream>>>(x, cluster, v, W_lin, out, N);
}

// Round 6
// 461.092 us; speedup vs baseline: 1.1597x; 1.1597x over previous
//
#include <hip/hip_runtime.h>

constexpr int IN_C   = 3;
constexpr int OUT_C  = 64;
constexpr int NB     = 27;
constexpr int WROW   = 84;               // 81 padded to 84 (16B-aligned rows)
constexpr int WFOLDT = OUT_C * WROW;     // 5376
constexpr int NXCD   = 8;

typedef float f32x4 __attribute__((ext_vector_type(4)));

// ---- stage A: XCD-private partial sums, workgroup-scope (L2-local) atomics ----
// Each wave adds into the partial plane of the XCD it is running on (read from
// HW_REG_XCC_ID, hwreg id 20 on gfx94x/950). A plane is only ever touched by
// waves on that XCD, so L2-local (workgroup-scope) atomics are correct by
// construction; no cross-XCD line migration.
__global__ void k_accum8(const int* __restrict__ cluster, const float* __restrict__ x,
                         float* __restrict__ partials, int N, int K) {
    unsigned xcc;
    asm("s_getreg_b32 %0, hwreg(20, 0, 32)" : "=s"(xcc));
    xcc &= (NXCD - 1);
    float* __restrict__ plane = partials + (size_t)xcc * (size_t)K * 4;

    int stride = gridDim.x * blockDim.x;
    for (int n = blockIdx.x * blockDim.x + threadIdx.x; n < N; n += stride) {
        int c = cluster[n];
        float x0 = x[n * 3 + 0];
        float x1 = x[n * 3 + 1];
        float x2 = x[n * 3 + 2];
        float* s = plane + (size_t)c * 4;
        __hip_atomic_fetch_add(s + 0, x0,  __ATOMIC_RELAXED, __HIP_MEMORY_SCOPE_WORKGROUP);
        __hip_atomic_fetch_add(s + 1, x1,  __ATOMIC_RELAXED, __HIP_MEMORY_SCOPE_WORKGROUP);
        __hip_atomic_fetch_add(s + 2, x2,  __ATOMIC_RELAXED, __HIP_MEMORY_SCOPE_WORKGROUP);
        __hip_atomic_fetch_add(s + 3, 1.f, __ATOMIC_RELAXED, __HIP_MEMORY_SCOPE_WORKGROUP);
    }
}

// ---- stage R: reduce 8 planes -> pooled means; sentinel row at K ----
__global__ void k_reduce(const float4* __restrict__ partials, float4* __restrict__ pooled,
                         int K) {
    int k = blockIdx.x * blockDim.x + threadIdx.x;
    if (k < K) {
        float sx = 0.f, sy = 0.f, sz = 0.f, ct = 0.f;
        #pragma unroll
        for (int p = 0; p < NXCD; ++p) {
            float4 s = partials[(size_t)p * K + k];
            sx += s.x; sy += s.y; sz += s.z; ct += s.w;
        }
        float inv = 1.0f / fmaxf(ct, 1.0f);
        pooled[k] = make_float4(sx * inv, sy * inv, sz * inv, 0.f);
    } else if (k == K) {
        pooled[K] = make_float4(0.f, 0.f, 0.f, 0.f);   // sentinel for masked neighbors
    }
}

// ---- stage B: fold W_conv with W_lin[3:,:], TRANSPOSED: WcT[j*84 + (o*3+i)] ----
__global__ void k_fold(const float* __restrict__ Wc, const float* __restrict__ Wl,
                       float* __restrict__ WcT) {
    int t = blockIdx.x * blockDim.x + threadIdx.x;
    if (t >= WFOLDT) return;
    int j = t / WROW;
    int f = t % WROW;     // f = o*3+i
    float acc = 0.f;
    if (f < NB * IN_C) {
        #pragma unroll
        for (int j2 = 0; j2 < OUT_C; ++j2)
            acc = fmaf(Wc[f * 64 + j2], Wl[(IN_C + j2) * OUT_C + j], acc);
    }
    WcT[t] = acc;
}

// ---- stage C: cluster-parallel. lane = cluster, loop over 64 channels. ----
__global__ __launch_bounds__(256) void
k_conv(const int* __restrict__ nb, const float4* __restrict__ pooled4,
       const float* __restrict__ WcT, const float* __restrict__ b_lin,
       float* __restrict__ v, int K) {
    __shared__ float xpose[4 * 64 * 17];     // 17408 B, per-wave slices
    const int lane = threadIdx.x & 63;
    const int wv   = threadIdx.x >> 6;
    const int wid  = (blockIdx.x * blockDim.x + threadIdx.x) >> 6;
    const int base = wid * 64;
    if (base >= K) return;
    const int kme = min(base + lane, K - 1);

    const int* nbrow = nb + (size_t)kme * NB;
    const unsigned uK = (unsigned)K;

    // 27 per-lane gathers; -1 maps (unsigned min) to zero sentinel row at K
    float4 p[NB];
    #pragma unroll
    for (int o = 0; o < NB; ++o) {
        unsigned s = min((unsigned)nbrow[o], uK);
        p[o] = pooled4[s];
    }

    float* xb = xpose + wv * (64 * 17);
    const int c4 = lane >> 4, jloc = lane & 15;

    #pragma unroll 1
    for (int jb = 0; jb < 4; ++jb) {
        #pragma unroll 2
        for (int jl = 0; jl < 16; ++jl) {
            const int j = jb * 16 + jl;
            const float* __restrict__ wj = WcT + j * WROW;   // wave-uniform row
            float a0 = b_lin[j], a1 = 0.f, a2 = 0.f;
            #pragma unroll
            for (int o = 0; o < NB; ++o) {
                a0 = fmaf(p[o].x, wj[o * 3 + 0], a0);
                a1 = fmaf(p[o].y, wj[o * 3 + 1], a1);
                a2 = fmaf(p[o].z, wj[o * 3 + 2], a2);
            }
            xb[lane * 17 + jl] = a0 + a1 + a2;               // 2-way banks: free
        }
        // transpose store: 16 coalesced 256B store instrs per jb
        #pragma unroll
        for (int cg = 0; cg < 16; ++cg) {
            int cl = cg * 4 + c4;
            int kk = base + cl;
            if (kk < K)
                v[(size_t)kk * OUT_C + jb * 16 + jloc] = xb[cl * 17 + jloc];
        }
    }
}

// ---- stage D: u[n] = x[n] @ W_lin[0:3] + v[cluster[n]] ; 4 pts/wave, float4 IO ----
__global__ void k_point(const float* __restrict__ x, const int* __restrict__ cluster,
                        const float* __restrict__ v, const float* __restrict__ Wl,
                        float* __restrict__ out, int N) {
    int lane = threadIdx.x & 63;
    int sub  = lane >> 4;
    int jj   = (lane & 15) * 4;
    int gwid   = (blockIdx.x * blockDim.x + threadIdx.x) >> 6;
    int nwaves = (gridDim.x * blockDim.x) >> 6;

    float4 w0 = *reinterpret_cast<const float4*>(Wl + 0 * OUT_C + jj);
    float4 w1 = *reinterpret_cast<const float4*>(Wl + 1 * OUT_C + jj);
    float4 w2 = *reinterpret_cast<const float4*>(Wl + 2 * OUT_C + jj);

    for (int base = gwid * 4; base < N; base += nwaves * 4) {
        int n = base + sub;
        if (n < N) {
            int c  = cluster[n];
            float x0 = x[n * 3 + 0];
            float x1 = x[n * 3 + 1];
            float x2 = x[n * 3 + 2];
            float4 acc = *reinterpret_cast<const float4*>(v + (size_t)c * OUT_C + jj);
            acc.x = fmaf(x0, w0.x, fmaf(x1, w1.x, fmaf(x2, w2.x, acc.x)));
            acc.y = fmaf(x0, w0.y, fmaf(x1, w1.y, fmaf(x2, w2.y, acc.y)));
            acc.z = fmaf(x0, w0.z, fmaf(x1, w1.z, fmaf(x2, w2.z, acc.z)));
            acc.w = fmaf(x0, w0.w, fmaf(x1, w1.w, fmaf(x2, w2.w, acc.w)));
            // nontemporal: don't let the 256MB output evict v from L2/L3
            f32x4 av = {acc.x, acc.y, acc.z, acc.w};
            __builtin_nontemporal_store(av,
                reinterpret_cast<f32x4*>(out + (size_t)n * OUT_C + jj));
        }
    }
}

extern "C" void kernel_launch(void* const* d_in, const int* in_sizes, int n_in,
                              void* d_out, int out_size, void* d_ws, size_t ws_size,
                              hipStream_t stream) {
    const float* x      = (const float*)d_in[0];
    const int*   cluster= (const int*)  d_in[1];
    const int*   nb     = (const int*)  d_in[2];
    const float* W_conv = (const float*)d_in[3];
    const float* W_lin  = (const float*)d_in[4];
    const float* b_lin  = (const float*)d_in[5];
    float* out = (float*)d_out;

    const int N = in_sizes[1];         // 1,000,000
    const int K = in_sizes[2] / NB;    // 200,000

    // workspace layout
    char* ws = (char*)d_ws;
    float4* pooled4 = (float4*)ws;                     // (K+1) * 16 B (sentinel at K)
    size_t off = (size_t)(K + 1) * sizeof(float4);
    off = ((off + 255) / 256) * 256;
    float* WcT = (float*)(ws + off);                   // 21504 B
    off += ((WFOLDT * sizeof(float) + 255) / 256) * 256;
    float* v = (float*)(ws + off);                     // K * 64 * 4 B (51.2 MB)
    // partials (8 planes * K * float4 = 25.6 MB) alias the v region:
    // consumed by k_reduce before k_conv overwrites v.
    float* partials = v;

    k_fold <<<(WFOLDT + 255) / 256, 256, 0, stream>>>(W_conv, W_lin, WcT);

    hipMemsetAsync(partials, 0, (size_t)NXCD * K * 4 * sizeof(float), stream);
    k_accum8<<<2048, 256, 0, stream>>>(cluster, x, partials, N, K);
    k_reduce<<<(K + 1 + 255) / 256, 256, 0, stream>>>((const float4*)partials, pooled4, K);

    int conv_waves  = (K + 63) / 64;                   // 3125
    int conv_blocks = (conv_waves + 3) / 4;            // 782
    k_conv <<<conv_blocks, 256, 0, stream>>>(nb, pooled4, WcT, b_lin, v, K);

    k_point<<<2048, 256, 0, stream>>>(x, cluster, v, W_lin, out, N);
}

// Round 7
// 349.068 us; speedup vs baseline: 1.5319x; 1.3209x over previous
//
#include <hip/hip_runtime.h>

constexpr int IN_C   = 3;
constexpr int OUT_C  = 64;
constexpr int NB     = 27;
constexpr int WROW   = 84;               // 81 padded to 84 (16B-aligned rows)
constexpr int WFOLDT = OUT_C * WROW;     // 5376
constexpr int CR     = 2048;             // clusters per range (32 KB LDS bins)
constexpr int NS     = 16;               // point slices

typedef float f32x4 __attribute__((ext_vector_type(4)));

// ---- stage A: range x slice LDS binning; ZERO global atomics ----
// Block (r,s): owns clusters [r*CR, r*CR+CR), scans point-slice s,
// accumulates in-range points into LDS bins, then writes its full bin range
// as plain coalesced float4 stores into partial plane s. No memset needed:
// every (r,s) plane region is fully overwritten each launch.
__global__ __launch_bounds__(256) void
k_poolscan(const int* __restrict__ cluster, const float* __restrict__ x,
           float4* __restrict__ partials, int N, int K, int R) {
    __shared__ float bins[CR * 4];
    const int tid = threadIdx.x;
    const int r   = blockIdx.x % R;
    const int s   = blockIdx.x / R;
    const unsigned base = (unsigned)r * CR;

    for (int i = tid; i < CR * 4; i += 256) bins[i] = 0.f;
    __syncthreads();

    const int P4 = N >> 2;               // uint4 count
    const int Q  = P4 / NS;
    const int i1 = (s == NS - 1) ? P4 : (s + 1) * Q;
    const uint4* __restrict__ cl4 = reinterpret_cast<const uint4*>(cluster);

    int i = s * Q + tid;
    uint4 c = (i < i1) ? cl4[i] : make_uint4(~0u, ~0u, ~0u, ~0u);
    while (i < i1) {
        const int inext = i + 256;
        uint4 cn = (inext < i1) ? cl4[inext] : make_uint4(~0u, ~0u, ~0u, ~0u);

        const unsigned r0 = c.x - base, r1 = c.y - base, r2 = c.z - base, r3 = c.w - base;
        const bool m0 = r0 < CR, m1 = r1 < CR, m2 = r2 < CR, m3 = r3 < CR;
        const int n = i * 4;

        // grouped conditional gathers (issue all before the LDS atomics)
        float a0=0.f,a1=0.f,a2=0.f, b0=0.f,b1=0.f,b2=0.f;
        float d0=0.f,d1=0.f,d2=0.f, e0=0.f,e1=0.f,e2=0.f;
        if (m0) { a0 = x[3*n+0];  a1 = x[3*n+1];  a2 = x[3*n+2]; }
        if (m1) { b0 = x[3*n+3];  b1 = x[3*n+4];  b2 = x[3*n+5]; }
        if (m2) { d0 = x[3*n+6];  d1 = x[3*n+7];  d2 = x[3*n+8]; }
        if (m3) { e0 = x[3*n+9];  e1 = x[3*n+10]; e2 = x[3*n+11]; }

        if (m0) { atomicAdd(&bins[r0*4+0], a0); atomicAdd(&bins[r0*4+1], a1);
                  atomicAdd(&bins[r0*4+2], a2); atomicAdd(&bins[r0*4+3], 1.f); }
        if (m1) { atomicAdd(&bins[r1*4+0], b0); atomicAdd(&bins[r1*4+1], b1);
                  atomicAdd(&bins[r1*4+2], b2); atomicAdd(&bins[r1*4+3], 1.f); }
        if (m2) { atomicAdd(&bins[r2*4+0], d0); atomicAdd(&bins[r2*4+1], d1);
                  atomicAdd(&bins[r2*4+2], d2); atomicAdd(&bins[r2*4+3], 1.f); }
        if (m3) { atomicAdd(&bins[r3*4+0], e0); atomicAdd(&bins[r3*4+1], e1);
                  atomicAdd(&bins[r3*4+2], e2); atomicAdd(&bins[r3*4+3], 1.f); }

        c = cn; i = inext;
    }
    // scalar tail (N % 4), handled by last slice only
    if (s == NS - 1) {
        for (int n = P4 * 4 + tid; n < N; n += 256) {
            unsigned rr = (unsigned)cluster[n] - base;
            if (rr < CR) {
                atomicAdd(&bins[rr*4+0], x[3*n+0]);
                atomicAdd(&bins[rr*4+1], x[3*n+1]);
                atomicAdd(&bins[rr*4+2], x[3*n+2]);
                atomicAdd(&bins[rr*4+3], 1.f);
            }
        }
    }
    __syncthreads();

    // flush full range, coalesced float4 stores into plane s
    float4* __restrict__ plane = partials + (size_t)s * K;
    for (int t = tid; t < CR; t += 256) {
        int k = (int)base + t;
        if (k < K)
            plane[k] = make_float4(bins[t*4+0], bins[t*4+1], bins[t*4+2], bins[t*4+3]);
    }
}

// ---- stage R: reduce NS planes -> pooled means; sentinel row at K ----
__global__ void k_reduce(const float4* __restrict__ partials, float4* __restrict__ pooled,
                         int K) {
    int k = blockIdx.x * blockDim.x + threadIdx.x;
    if (k < K) {
        float sx = 0.f, sy = 0.f, sz = 0.f, ct = 0.f;
        #pragma unroll
        for (int p = 0; p < NS; ++p) {
            float4 s = partials[(size_t)p * K + k];
            sx += s.x; sy += s.y; sz += s.z; ct += s.w;
        }
        float inv = 1.0f / fmaxf(ct, 1.0f);
        pooled[k] = make_float4(sx * inv, sy * inv, sz * inv, 0.f);
    } else if (k == K) {
        pooled[K] = make_float4(0.f, 0.f, 0.f, 0.f);   // sentinel for masked neighbors
    }
}

// ---- stage B: fold W_conv with W_lin[3:,:], TRANSPOSED: WcT[j*84 + (o*3+i)] ----
__global__ void k_fold(const float* __restrict__ Wc, const float* __restrict__ Wl,
                       float* __restrict__ WcT) {
    int t = blockIdx.x * blockDim.x + threadIdx.x;
    if (t >= WFOLDT) return;
    int j = t / WROW;
    int f = t % WROW;     // f = o*3+i
    float acc = 0.f;
    if (f < NB * IN_C) {
        #pragma unroll
        for (int j2 = 0; j2 < OUT_C; ++j2)
            acc = fmaf(Wc[f * 64 + j2], Wl[(IN_C + j2) * OUT_C + j], acc);
    }
    WcT[t] = acc;
}

// ---- stage C: cluster-parallel. lane = cluster, loop over 64 channels. ----
__global__ __launch_bounds__(256) void
k_conv(const int* __restrict__ nb, const float4* __restrict__ pooled4,
       const float* __restrict__ WcT, const float* __restrict__ b_lin,
       float* __restrict__ v, int K) {
    __shared__ float xpose[4 * 64 * 17];     // 17408 B, per-wave slices
    const int lane = threadIdx.x & 63;
    const int wv   = threadIdx.x >> 6;
    const int wid  = (blockIdx.x * blockDim.x + threadIdx.x) >> 6;
    const int base = wid * 64;
    if (base >= K) return;
    const int kme = min(base + lane, K - 1);

    const int* nbrow = nb + (size_t)kme * NB;
    const unsigned uK = (unsigned)K;

    // 27 per-lane gathers; -1 maps (unsigned min) to zero sentinel row at K
    float4 p[NB];
    #pragma unroll
    for (int o = 0; o < NB; ++o) {
        unsigned s = min((unsigned)nbrow[o], uK);
        p[o] = pooled4[s];
    }

    float* xb = xpose + wv * (64 * 17);
    const int c4 = lane >> 4, jloc = lane & 15;

    #pragma unroll 1
    for (int jb = 0; jb < 4; ++jb) {
        #pragma unroll 2
        for (int jl = 0; jl < 16; ++jl) {
            const int j = jb * 16 + jl;
            const float* __restrict__ wj = WcT + j * WROW;   // wave-uniform row
            float a0 = b_lin[j], a1 = 0.f, a2 = 0.f;
            #pragma unroll
            for (int o = 0; o < NB; ++o) {
                a0 = fmaf(p[o].x, wj[o * 3 + 0], a0);
                a1 = fmaf(p[o].y, wj[o * 3 + 1], a1);
                a2 = fmaf(p[o].z, wj[o * 3 + 2], a2);
            }
            xb[lane * 17 + jl] = a0 + a1 + a2;               // 2-way banks: free
        }
        // transpose store: 16 coalesced 256B store instrs per jb
        #pragma unroll
        for (int cg = 0; cg < 16; ++cg) {
            int cl = cg * 4 + c4;
            int kk = base + cl;
            if (kk < K)
                v[(size_t)kk * OUT_C + jb * 16 + jloc] = xb[cl * 17 + jloc];
        }
    }
}

// ---- stage D: u[n] = x[n] @ W_lin[0:3] + v[cluster[n]] ; 4 pts/wave, float4 IO ----
__global__ void k_point(const float* __restrict__ x, const int* __restrict__ cluster,
                        const float* __restrict__ v, const float* __restrict__ Wl,
                        float* __restrict__ out, int N) {
    int lane = threadIdx.x & 63;
    int sub  = lane >> 4;
    int jj   = (lane & 15) * 4;
    int gwid   = (blockIdx.x * blockDim.x + threadIdx.x) >> 6;
    int nwaves = (gridDim.x * blockDim.x) >> 6;

    float4 w0 = *reinterpret_cast<const float4*>(Wl + 0 * OUT_C + jj);
    float4 w1 = *reinterpret_cast<const float4*>(Wl + 1 * OUT_C + jj);
    float4 w2 = *reinterpret_cast<const float4*>(Wl + 2 * OUT_C + jj);

    for (int base = gwid * 4; base < N; base += nwaves * 4) {
        int n = base + sub;
        if (n < N) {
            int c  = cluster[n];
            float x0 = x[n * 3 + 0];
            float x1 = x[n * 3 + 1];
            float x2 = x[n * 3 + 2];
            float4 acc = *reinterpret_cast<const float4*>(v + (size_t)c * OUT_C + jj);
            acc.x = fmaf(x0, w0.x, fmaf(x1, w1.x, fmaf(x2, w2.x, acc.x)));
            acc.y = fmaf(x0, w0.y, fmaf(x1, w1.y, fmaf(x2, w2.y, acc.y)));
            acc.z = fmaf(x0, w0.z, fmaf(x1, w1.z, fmaf(x2, w2.z, acc.z)));
            acc.w = fmaf(x0, w0.w, fmaf(x1, w1.w, fmaf(x2, w2.w, acc.w)));
            // nontemporal: don't let the 256MB output evict v from L2/L3
            f32x4 av = {acc.x, acc.y, acc.z, acc.w};
            __builtin_nontemporal_store(av,
                reinterpret_cast<f32x4*>(out + (size_t)n * OUT_C + jj));
        }
    }
}

extern "C" void kernel_launch(void* const* d_in, const int* in_sizes, int n_in,
                              void* d_out, int out_size, void* d_ws, size_t ws_size,
                              hipStream_t stream) {
    const float* x      = (const float*)d_in[0];
    const int*   cluster= (const int*)  d_in[1];
    const int*   nb     = (const int*)  d_in[2];
    const float* W_conv = (const float*)d_in[3];
    const float* W_lin  = (const float*)d_in[4];
    const float* b_lin  = (const float*)d_in[5];
    float* out = (float*)d_out;

    const int N = in_sizes[1];         // 1,000,000
    const int K = in_sizes[2] / NB;    // 200,000

    // workspace layout
    char* ws = (char*)d_ws;
    float4* pooled4 = (float4*)ws;                     // (K+1) * 16 B (sentinel at K)
    size_t off = (size_t)(K + 1) * sizeof(float4);
    off = ((off + 255) / 256) * 256;
    float* WcT = (float*)(ws + off);                   // 21504 B
    off += ((WFOLDT * sizeof(float) + 255) / 256) * 256;
    float* v = (float*)(ws + off);                     // K * 64 * 4 B (51.2 MB)
    // partials: NS planes * K * 16 B = 51.2 MB, aliasing v (consumed by
    // k_reduce before k_conv overwrites v).
    float4* partials = (float4*)v;

    k_fold <<<(WFOLDT + 255) / 256, 256, 0, stream>>>(W_conv, W_lin, WcT);

    const int R = (K + CR - 1) / CR;                   // 98 ranges
    k_poolscan<<<R * NS, 256, 0, stream>>>(cluster, x, partials, N, K, R);
    k_reduce<<<(K + 1 + 255) / 256, 256, 0, stream>>>(partials, pooled4, K);

    int conv_waves  = (K + 63) / 64;                   // 3125
    int conv_blocks = (conv_waves + 3) / 4;            // 782
    k_conv <<<conv_blocks, 256, 0, stream>>>(nb, pooled4, WcT, b_lin, v, K);

    k_point<<<2048, 256, 0, stream>>>(x, cluster, v, W_lin, out, N);
}

// Round 8
// 288.100 us; speedup vs baseline: 1.8561x; 1.2116x over previous
//
#include <hip/hip_runtime.h>

constexpr int IN_C   = 3;
constexpr int OUT_C  = 64;
constexpr int NB     = 27;
constexpr int WROW   = 84;               // 81 padded to 84 (16B-aligned rows)
constexpr int WFOLDT = OUT_C * WROW;     // 5376
constexpr int CR     = 2048;             // clusters per range (32 KB LDS bins)
constexpr int NS     = 16;               // point slices

typedef float f32x4 __attribute__((ext_vector_type(4)));

// ---- stage A: range x slice LDS binning; ZERO global atomics ----
__global__ __launch_bounds__(256) void
k_poolscan(const int* __restrict__ cluster, const float* __restrict__ x,
           float4* __restrict__ partials, int N, int K, int R) {
    __shared__ float bins[CR * 4];
    const int tid = threadIdx.x;
    const int r   = blockIdx.x % R;
    const int s   = blockIdx.x / R;
    const unsigned base = (unsigned)r * CR;

    for (int i = tid; i < CR * 4; i += 256) bins[i] = 0.f;
    __syncthreads();

    const int P4 = N >> 2;               // uint4 count
    const int Q  = P4 / NS;
    const int i1 = (s == NS - 1) ? P4 : (s + 1) * Q;
    const uint4* __restrict__ cl4 = reinterpret_cast<const uint4*>(cluster);

    int i = s * Q + tid;
    uint4 c = (i < i1) ? cl4[i] : make_uint4(~0u, ~0u, ~0u, ~0u);
    while (i < i1) {
        const int inext = i + 256;
        uint4 cn = (inext < i1) ? cl4[inext] : make_uint4(~0u, ~0u, ~0u, ~0u);

        const unsigned r0 = c.x - base, r1 = c.y - base, r2 = c.z - base, r3 = c.w - base;
        const bool m0 = r0 < CR, m1 = r1 < CR, m2 = r2 < CR, m3 = r3 < CR;
        const int n = i * 4;

        float a0=0.f,a1=0.f,a2=0.f, b0=0.f,b1=0.f,b2=0.f;
        float d0=0.f,d1=0.f,d2=0.f, e0=0.f,e1=0.f,e2=0.f;
        if (m0) { a0 = x[3*n+0];  a1 = x[3*n+1];  a2 = x[3*n+2]; }
        if (m1) { b0 = x[3*n+3];  b1 = x[3*n+4];  b2 = x[3*n+5]; }
        if (m2) { d0 = x[3*n+6];  d1 = x[3*n+7];  d2 = x[3*n+8]; }
        if (m3) { e0 = x[3*n+9];  e1 = x[3*n+10]; e2 = x[3*n+11]; }

        if (m0) { atomicAdd(&bins[r0*4+0], a0); atomicAdd(&bins[r0*4+1], a1);
                  atomicAdd(&bins[r0*4+2], a2); atomicAdd(&bins[r0*4+3], 1.f); }
        if (m1) { atomicAdd(&bins[r1*4+0], b0); atomicAdd(&bins[r1*4+1], b1);
                  atomicAdd(&bins[r1*4+2], b2); atomicAdd(&bins[r1*4+3], 1.f); }
        if (m2) { atomicAdd(&bins[r2*4+0], d0); atomicAdd(&bins[r2*4+1], d1);
                  atomicAdd(&bins[r2*4+2], d2); atomicAdd(&bins[r2*4+3], 1.f); }
        if (m3) { atomicAdd(&bins[r3*4+0], e0); atomicAdd(&bins[r3*4+1], e1);
                  atomicAdd(&bins[r3*4+2], e2); atomicAdd(&bins[r3*4+3], 1.f); }

        c = cn; i = inext;
    }
    if (s == NS - 1) {
        for (int n = P4 * 4 + tid; n < N; n += 256) {
            unsigned rr = (unsigned)cluster[n] - base;
            if (rr < CR) {
                atomicAdd(&bins[rr*4+0], x[3*n+0]);
                atomicAdd(&bins[rr*4+1], x[3*n+1]);
                atomicAdd(&bins[rr*4+2], x[3*n+2]);
                atomicAdd(&bins[rr*4+3], 1.f);
            }
        }
    }
    __syncthreads();

    float4* __restrict__ plane = partials + (size_t)s * K;
    for (int t = tid; t < CR; t += 256) {
        int k = (int)base + t;
        if (k < K)
            plane[k] = make_float4(bins[t*4+0], bins[t*4+1], bins[t*4+2], bins[t*4+3]);
    }
}

// ---- stage R: reduce NS planes -> pooled means; sentinel row at K ----
__global__ void k_reduce(const float4* __restrict__ partials, float4* __restrict__ pooled,
                         int K) {
    int k = blockIdx.x * blockDim.x + threadIdx.x;
    if (k < K) {
        float sx = 0.f, sy = 0.f, sz = 0.f, ct = 0.f;
        #pragma unroll
        for (int p = 0; p < NS; ++p) {
            float4 s = partials[(size_t)p * K + k];
            sx += s.x; sy += s.y; sz += s.z; ct += s.w;
        }
        float inv = 1.0f / fmaxf(ct, 1.0f);
        pooled[k] = make_float4(sx * inv, sy * inv, sz * inv, 0.f);
    } else if (k == K) {
        pooled[K] = make_float4(0.f, 0.f, 0.f, 0.f);
    }
}

// ---- stage B: fold W_conv with W_lin[3:,:], TRANSPOSED: WcT[j*84 + (o*3+i)] ----
__global__ void k_fold(const float* __restrict__ Wc, const float* __restrict__ Wl,
                       float* __restrict__ WcT) {
    int t = blockIdx.x * blockDim.x + threadIdx.x;
    if (t >= WFOLDT) return;
    int j = t / WROW;
    int f = t % WROW;     // f = o*3+i
    float acc = 0.f;
    if (f < NB * IN_C) {
        #pragma unroll
        for (int j2 = 0; j2 < OUT_C; ++j2)
            acc = fmaf(Wc[f * 64 + j2], Wl[(IN_C + j2) * OUT_C + j], acc);
    }
    WcT[t] = acc;
}

// ---- stage C: lane = cluster, channels in loop; weights staged in LDS ----
// Weight reads are uniform-address ds_read broadcasts (no bank conflicts,
// ~100cy, pipelined under the FMAs) instead of per-channel scalar-mem loads.
__global__ __launch_bounds__(256) void
k_conv(const int* __restrict__ nb, const float4* __restrict__ pooled4,
       const float* __restrict__ WcT, const float* __restrict__ b_lin,
       float* __restrict__ v, int K) {
    __shared__ float wsm[WFOLDT];            // 21504 B: [j][84]
    __shared__ float bsm[OUT_C];             // 256 B
    __shared__ float xpose[4 * 64 * 17];     // 17408 B, per-wave slices
    // staging (uniform across block, before any early exit)
    for (int t = threadIdx.x; t < WFOLDT; t += 256) wsm[t] = WcT[t];
    if (threadIdx.x < OUT_C) bsm[threadIdx.x] = b_lin[threadIdx.x];
    __syncthreads();

    const int lane = threadIdx.x & 63;
    const int wv   = threadIdx.x >> 6;
    const int wid  = (blockIdx.x * blockDim.x + threadIdx.x) >> 6;
    const int base = wid * 64;
    if (base >= K) return;
    const int kme = min(base + lane, K - 1);

    const int* nbrow = nb + (size_t)kme * NB;
    const unsigned uK = (unsigned)K;

    // 27 per-lane gathers; -1 maps (unsigned min) to zero sentinel row at K
    float4 p[NB];
    #pragma unroll
    for (int o = 0; o < NB; ++o) {
        unsigned s = min((unsigned)nbrow[o], uK);
        p[o] = pooled4[s];
    }

    float* xb = xpose + wv * (64 * 17);
    const int c4 = lane >> 4, jloc = lane & 15;

    #pragma unroll 1
    for (int jb = 0; jb < 4; ++jb) {
        #pragma unroll 2
        for (int jl = 0; jl < 16; ++jl) {
            const int j = jb * 16 + jl;
            const float* wj = wsm + j * WROW;        // uniform LDS row
            float a0 = bsm[j], a1 = 0.f, a2 = 0.f;
            #pragma unroll
            for (int o = 0; o < NB; ++o) {
                a0 = fmaf(p[o].x, wj[o * 3 + 0], a0);
                a1 = fmaf(p[o].y, wj[o * 3 + 1], a1);
                a2 = fmaf(p[o].z, wj[o * 3 + 2], a2);
            }
            xb[lane * 17 + jl] = a0 + a1 + a2;
        }
        // transpose store: 16 coalesced 256B store instrs per jb
        #pragma unroll
        for (int cg = 0; cg < 16; ++cg) {
            int cl = cg * 4 + c4;
            int kk = base + cl;
            if (kk < K)
                v[(size_t)kk * OUT_C + jb * 16 + jloc] = xb[cl * 17 + jloc];
        }
    }
}

// ---- stage D: u[n] = x[n] @ W_lin[0:3] + v[cluster[n]] ; 4 pts/wave, float4 IO ----
__global__ void k_point(const float* __restrict__ x, const int* __restrict__ cluster,
                        const float* __restrict__ v, const float* __restrict__ Wl,
                        float* __restrict__ out, int N) {
    int lane = threadIdx.x & 63;
    int sub  = lane >> 4;
    int jj   = (lane & 15) * 4;
    int gwid   = (blockIdx.x * blockDim.x + threadIdx.x) >> 6;
    int nwaves = (gridDim.x * blockDim.x) >> 6;

    float4 w0 = *reinterpret_cast<const float4*>(Wl + 0 * OUT_C + jj);
    float4 w1 = *reinterpret_cast<const float4*>(Wl + 1 * OUT_C + jj);
    float4 w2 = *reinterpret_cast<const float4*>(Wl + 2 * OUT_C + jj);

    for (int base = gwid * 4; base < N; base += nwaves * 4) {
        int n = base + sub;
        if (n < N) {
            int c  = cluster[n];
            float x0 = x[n * 3 + 0];
            float x1 = x[n * 3 + 1];
            float x2 = x[n * 3 + 2];
            float4 acc = *reinterpret_cast<const float4*>(v + (size_t)c * OUT_C + jj);
            acc.x = fmaf(x0, w0.x, fmaf(x1, w1.x, fmaf(x2, w2.x, acc.x)));
            acc.y = fmaf(x0, w0.y, fmaf(x1, w1.y, fmaf(x2, w2.y, acc.y)));
            acc.z = fmaf(x0, w0.z, fmaf(x1, w1.z, fmaf(x2, w2.z, acc.z)));
            acc.w = fmaf(x0, w0.w, fmaf(x1, w1.w, fmaf(x2, w2.w, acc.w)));
            f32x4 av = {acc.x, acc.y, acc.z, acc.w};
            __builtin_nontemporal_store(av,
                reinterpret_cast<f32x4*>(out + (size_t)n * OUT_C + jj));
        }
    }
}

extern "C" void kernel_launch(void* const* d_in, const int* in_sizes, int n_in,
                              void* d_out, int out_size, void* d_ws, size_t ws_size,
                              hipStream_t stream) {
    const float* x      = (const float*)d_in[0];
    const int*   cluster= (const int*)  d_in[1];
    const int*   nb     = (const int*)  d_in[2];
    const float* W_conv = (const float*)d_in[3];
    const float* W_lin  = (const float*)d_in[4];
    const float* b_lin  = (const float*)d_in[5];
    float* out = (float*)d_out;

    const int N = in_sizes[1];         // 1,000,000
    const int K = in_sizes[2] / NB;    // 200,000

    // workspace layout
    char* ws = (char*)d_ws;
    float4* pooled4 = (float4*)ws;                     // (K+1) * 16 B (sentinel at K)
    size_t off = (size_t)(K + 1) * sizeof(float4);
    off = ((off + 255) / 256) * 256;
    float* WcT = (float*)(ws + off);                   // 21504 B
    off += ((WFOLDT * sizeof(float) + 255) / 256) * 256;
    float* v = (float*)(ws + off);                     // K * 64 * 4 B (51.2 MB)
    float4* partials = (float4*)v;                     // NS*K*16B = 51.2 MB, aliases v

    k_fold <<<(WFOLDT + 255) / 256, 256, 0, stream>>>(W_conv, W_lin, WcT);

    const int R = (K + CR - 1) / CR;                   // 98 ranges
    k_poolscan<<<R * NS, 256, 0, stream>>>(cluster, x, partials, N, K, R);
    k_reduce<<<(K + 1 + 255) / 256, 256, 0, stream>>>(partials, pooled4, K);

    int conv_waves  = (K + 63) / 64;                   // 3125
    int conv_blocks = (conv_waves + 3) / 4;            // 782
    k_conv <<<conv_blocks, 256, 0, stream>>>(nb, pooled4, WcT, b_lin, v, K);

    k_point<<<2048, 256, 0, stream>>>(x, cluster, v, W_lin, out, N);
}

// Round 9
// 235.581 us; speedup vs baseline: 2.2698x; 1.2229x over previous
//
#include <hip/hip_runtime.h>

constexpr int IN_C   = 3;
constexpr int OUT_C  = 64;
constexpr int NB     = 27;
constexpr int CR     = 2048;             // clusters per range (32 KB LDS bins)
constexpr int NS     = 16;               // point slices
constexpr int WPK_N  = 12 * 64 * 8;      // 6144 bf16 fragment elements

typedef float f32x4 __attribute__((ext_vector_type(4)));
typedef short bf16x8 __attribute__((ext_vector_type(8)));

__device__ __forceinline__ unsigned short f2bf(float f) {
    unsigned u = __builtin_bit_cast(unsigned, f);
    u += 0x7fffu + ((u >> 16) & 1u);     // round-to-nearest-even
    return (unsigned short)(u >> 16);
}

// ---- stage A: range x slice LDS binning; ZERO global atomics ----
__global__ __launch_bounds__(256) void
k_poolscan(const int* __restrict__ cluster, const float* __restrict__ x,
           float4* __restrict__ partials, int N, int K, int R) {
    __shared__ float bins[CR * 4];
    const int tid = threadIdx.x;
    const int r   = blockIdx.x % R;
    const int s   = blockIdx.x / R;
    const unsigned base = (unsigned)r * CR;

    for (int i = tid; i < CR * 4; i += 256) bins[i] = 0.f;
    __syncthreads();

    const int P4 = N >> 2;               // uint4 count
    const int Q  = P4 / NS;
    const int i1 = (s == NS - 1) ? P4 : (s + 1) * Q;
    const uint4* __restrict__ cl4 = reinterpret_cast<const uint4*>(cluster);

    int i = s * Q + tid;
    uint4 c = (i < i1) ? cl4[i] : make_uint4(~0u, ~0u, ~0u, ~0u);
    while (i < i1) {
        const int inext = i + 256;
        uint4 cn = (inext < i1) ? cl4[inext] : make_uint4(~0u, ~0u, ~0u, ~0u);

        const unsigned r0 = c.x - base, r1 = c.y - base, r2 = c.z - base, r3 = c.w - base;
        const bool m0 = r0 < CR, m1 = r1 < CR, m2 = r2 < CR, m3 = r3 < CR;
        const int n = i * 4;

        float a0=0.f,a1=0.f,a2=0.f, b0=0.f,b1=0.f,b2=0.f;
        float d0=0.f,d1=0.f,d2=0.f, e0=0.f,e1=0.f,e2=0.f;
        if (m0) { a0 = x[3*n+0];  a1 = x[3*n+1];  a2 = x[3*n+2]; }
        if (m1) { b0 = x[3*n+3];  b1 = x[3*n+4];  b2 = x[3*n+5]; }
        if (m2) { d0 = x[3*n+6];  d1 = x[3*n+7];  d2 = x[3*n+8]; }
        if (m3) { e0 = x[3*n+9];  e1 = x[3*n+10]; e2 = x[3*n+11]; }

        if (m0) { atomicAdd(&bins[r0*4+0], a0); atomicAdd(&bins[r0*4+1], a1);
                  atomicAdd(&bins[r0*4+2], a2); atomicAdd(&bins[r0*4+3], 1.f); }
        if (m1) { atomicAdd(&bins[r1*4+0], b0); atomicAdd(&bins[r1*4+1], b1);
                  atomicAdd(&bins[r1*4+2], b2); atomicAdd(&bins[r1*4+3], 1.f); }
        if (m2) { atomicAdd(&bins[r2*4+0], d0); atomicAdd(&bins[r2*4+1], d1);
                  atomicAdd(&bins[r2*4+2], d2); atomicAdd(&bins[r2*4+3], 1.f); }
        if (m3) { atomicAdd(&bins[r3*4+0], e0); atomicAdd(&bins[r3*4+1], e1);
                  atomicAdd(&bins[r3*4+2], e2); atomicAdd(&bins[r3*4+3], 1.f); }

        c = cn; i = inext;
    }
    if (s == NS - 1) {
        for (int n = P4 * 4 + tid; n < N; n += 256) {
            unsigned rr = (unsigned)cluster[n] - base;
            if (rr < CR) {
                atomicAdd(&bins[rr*4+0], x[3*n+0]);
                atomicAdd(&bins[rr*4+1], x[3*n+1]);
                atomicAdd(&bins[rr*4+2], x[3*n+2]);
                atomicAdd(&bins[rr*4+3], 1.f);
            }
        }
    }
    __syncthreads();

    float4* __restrict__ plane = partials + (size_t)s * K;
    for (int t = tid; t < CR; t += 256) {
        int k = (int)base + t;
        if (k < K)
            plane[k] = make_float4(bins[t*4+0], bins[t*4+1], bins[t*4+2], bins[t*4+3]);
    }
}

// ---- stage R: reduce NS planes -> pooled means; sentinel row at K ----
__global__ void k_reduce(const float4* __restrict__ partials, float4* __restrict__ pooled,
                         int K) {
    int k = blockIdx.x * blockDim.x + threadIdx.x;
    if (k < K) {
        float sx = 0.f, sy = 0.f, sz = 0.f, ct = 0.f;
        #pragma unroll
        for (int p = 0; p < NS; ++p) {
            float4 s = partials[(size_t)p * K + k];
            sx += s.x; sy += s.y; sz += s.z; ct += s.w;
        }
        float inv = 1.0f / fmaxf(ct, 1.0f);
        pooled[k] = make_float4(sx * inv, sy * inv, sz * inv, 0.f);
    } else if (k == K) {
        pooled[K] = make_float4(0.f, 0.f, 0.f, 0.f);
    }
}

// ---- stage B: fold W_conv @ W_lin[3:,:] -> bf16, pre-packed in MFMA B-fragment
// order. Wfold[kk][ch], kk = o*3+i (0..80, zero for 81..95), 3 k-steps of 32.
// Fragment: tile st = s*4+t; lane l: n = 16t + (l&15), k = 32s + 8*(l>>4) + j.
// Flat index: st*512 + l*8 + j.
__global__ void k_fold(const float* __restrict__ Wc, const float* __restrict__ Wl,
                       unsigned short* __restrict__ Wpk) {
    int t = blockIdx.x * blockDim.x + threadIdx.x;
    if (t >= WPK_N) return;
    int j  = t & 7;
    int l  = (t >> 3) & 63;
    int st = t >> 9;
    int s  = st >> 2, tt = st & 3;
    int kk = 32 * s + 8 * (l >> 4) + j;
    int ch = 16 * tt + (l & 15);
    float acc = 0.f;
    if (kk < NB * IN_C) {
        #pragma unroll
        for (int j2 = 0; j2 < OUT_C; ++j2)
            acc = fmaf(Wc[kk * 64 + j2], Wl[(IN_C + j2) * OUT_C + ch], acc);
    }
    Wpk[t] = f2bf(acc);
}

// ---- stage C: MFMA conv. Block = 64 clusters; wave = 16 clusters x 64 ch. ----
// V[16x64] = A(G 16x96 bf16) . B(W 96x64 bf16) + bias, f32 accumulate.
__global__ __launch_bounds__(256) void
k_conv(const int* __restrict__ nb, const float4* __restrict__ pooled4,
       const unsigned short* __restrict__ Wpk, const float* __restrict__ b_lin,
       float* __restrict__ v, int K) {
    __shared__ float G[64][100];         // 25.6 KB; pad 100 -> <=2-way conflicts
    const int tid   = threadIdx.x;
    const int cbase = blockIdx.x * 64;

    // stage: gather pooled rows for this block's 64 clusters into LDS (kk-major)
    {
        const int c = tid & 63;
        const int og = tid >> 6;                      // 0..3
        for (int kk = 81 + og; kk < 100; kk += 4) G[c][kk] = 0.f;  // zero A-pad
        const int kglob = min(cbase + c, K - 1);
        const int* nbrow = nb + (size_t)kglob * NB;
        for (int o = og; o < NB; o += 4) {
            unsigned s = min((unsigned)nbrow[o], (unsigned)K);  // -1 -> sentinel K
            float4 p = pooled4[s];
            G[c][3*o+0] = p.x; G[c][3*o+1] = p.y; G[c][3*o+2] = p.z;
        }
    }
    __syncthreads();

    const int lane = tid & 63;
    const int wv   = tid >> 6;           // wave -> clusters [wv*16, +16)
    const int m    = lane & 15;          // A row / D col
    const int b    = lane >> 4;          // k-block / D row group

    // B fragments (12 tiles), 16B loads, L1-resident
    bf16x8 bw[12];
    const bf16x8* wp = reinterpret_cast<const bf16x8*>(Wpk);
    #pragma unroll
    for (int st = 0; st < 12; ++st) bw[st] = wp[st * 64 + lane];

    f32x4 acc[4];
    #pragma unroll
    for (int t = 0; t < 4; ++t) {
        float bb = b_lin[16 * t + m];    // D col = lane&15
        acc[t] = (f32x4){bb, bb, bb, bb};
    }

    const float* grow = &G[wv * 16 + m][0];
    #pragma unroll
    for (int s = 0; s < 3; ++s) {
        float4 g0 = *reinterpret_cast<const float4*>(grow + 32 * s + 8 * b);
        float4 g1 = *reinterpret_cast<const float4*>(grow + 32 * s + 8 * b + 4);
        bf16x8 af;
        af[0] = (short)f2bf(g0.x); af[1] = (short)f2bf(g0.y);
        af[2] = (short)f2bf(g0.z); af[3] = (short)f2bf(g0.w);
        af[4] = (short)f2bf(g1.x); af[5] = (short)f2bf(g1.y);
        af[6] = (short)f2bf(g1.z); af[7] = (short)f2bf(g1.w);
        #pragma unroll
        for (int t = 0; t < 4; ++t)
            acc[t] = __builtin_amdgcn_mfma_f32_16x16x32_bf16(af, bw[s * 4 + t], acc[t], 0, 0, 0);
    }

    // D: col = lane&15, row = (lane>>4)*4 + reg  [verified m89/m91]
    #pragma unroll
    for (int t = 0; t < 4; ++t) {
        #pragma unroll
        for (int r = 0; r < 4; ++r) {
            int crow = cbase + wv * 16 + 4 * b + r;
            if (crow < K)
                v[(size_t)crow * OUT_C + 16 * t + m] = acc[t][r];
        }
    }
}

// ---- stage D: u[n] = x[n] @ W_lin[0:3] + v[cluster[n]] ; 4 pts/wave, float4 IO ----
__global__ void k_point(const float* __restrict__ x, const int* __restrict__ cluster,
                        const float* __restrict__ v, const float* __restrict__ Wl,
                        float* __restrict__ out, int N) {
    int lane = threadIdx.x & 63;
    int sub  = lane >> 4;
    int jj   = (lane & 15) * 4;
    int gwid   = (blockIdx.x * blockDim.x + threadIdx.x) >> 6;
    int nwaves = (gridDim.x * blockDim.x) >> 6;

    float4 w0 = *reinterpret_cast<const float4*>(Wl + 0 * OUT_C + jj);
    float4 w1 = *reinterpret_cast<const float4*>(Wl + 1 * OUT_C + jj);
    float4 w2 = *reinterpret_cast<const float4*>(Wl + 2 * OUT_C + jj);

    for (int base = gwid * 4; base < N; base += nwaves * 4) {
        int n = base + sub;
        if (n < N) {
            int c  = cluster[n];
            float x0 = x[n * 3 + 0];
            float x1 = x[n * 3 + 1];
            float x2 = x[n * 3 + 2];
            float4 acc = *reinterpret_cast<const float4*>(v + (size_t)c * OUT_C + jj);
            acc.x = fmaf(x0, w0.x, fmaf(x1, w1.x, fmaf(x2, w2.x, acc.x)));
            acc.y = fmaf(x0, w0.y, fmaf(x1, w1.y, fmaf(x2, w2.y, acc.y)));
            acc.z = fmaf(x0, w0.z, fmaf(x1, w1.z, fmaf(x2, w2.z, acc.z)));
            acc.w = fmaf(x0, w0.w, fmaf(x1, w1.w, fmaf(x2, w2.w, acc.w)));
            f32x4 av = {acc.x, acc.y, acc.z, acc.w};
            __builtin_nontemporal_store(av,
                reinterpret_cast<f32x4*>(out + (size_t)n * OUT_C + jj));
        }
    }
}

extern "C" void kernel_launch(void* const* d_in, const int* in_sizes, int n_in,
                              void* d_out, int out_size, void* d_ws, size_t ws_size,
                              hipStream_t stream) {
    const float* x      = (const float*)d_in[0];
    const int*   cluster= (const int*)  d_in[1];
    const int*   nb     = (const int*)  d_in[2];
    const float* W_conv = (const float*)d_in[3];
    const float* W_lin  = (const float*)d_in[4];
    const float* b_lin  = (const float*)d_in[5];
    float* out = (float*)d_out;

    const int N = in_sizes[1];         // 1,000,000
    const int K = in_sizes[2] / NB;    // 200,000

    // workspace layout
    char* ws = (char*)d_ws;
    float4* pooled4 = (float4*)ws;                     // (K+1) * 16 B (sentinel at K)
    size_t off = (size_t)(K + 1) * sizeof(float4);
    off = ((off + 255) / 256) * 256;
    unsigned short* Wpk = (unsigned short*)(ws + off); // 12.3 KB packed bf16 weights
    off += ((WPK_N * sizeof(unsigned short) + 255) / 256) * 256;
    float* v = (float*)(ws + off);                     // K * 64 * 4 B (51.2 MB)
    float4* partials = (float4*)v;                     // NS*K*16B = 51.2 MB, aliases v

    k_fold <<<(WPK_N + 255) / 256, 256, 0, stream>>>(W_conv, W_lin, Wpk);

    const int R = (K + CR - 1) / CR;                   // 98 ranges
    k_poolscan<<<R * NS, 256, 0, stream>>>(cluster, x, partials, N, K, R);
    k_reduce<<<(K + 1 + 255) / 256, 256, 0, stream>>>(partials, pooled4, K);

    const int conv_blocks = (K + 63) / 64;             // 3125
    k_conv<<<conv_blocks, 256, 0, stream>>>(nb, pooled4, Wpk, b_lin, v, K);

    k_point<<<2048, 256, 0, stream>>>(x, cluster, v, W_lin, out, N);
}

// Round 10
// 220.786 us; speedup vs baseline: 2.4219x; 1.0670x over previous
//
#include <hip/hip_runtime.h>

constexpr int IN_C   = 3;
constexpr int OUT_C  = 64;
constexpr int NB     = 27;
constexpr int CR     = 4096;             // clusters per range (64 KB LDS bins)
constexpr int NS     = 16;               // point slices
constexpr int WPK_N  = 12 * 64 * 8;      // 6144 bf16 fragment elements

typedef float f32x4 __attribute__((ext_vector_type(4)));
typedef short bf16x8 __attribute__((ext_vector_type(8)));

__device__ __forceinline__ unsigned short f2bf(float f) {
    unsigned u = __builtin_bit_cast(unsigned, f);
    u += 0x7fffu + ((u >> 16) & 1u);     // round-to-nearest-even
    return (unsigned short)(u >> 16);
}
__device__ __forceinline__ float bflo(unsigned u) {
    return __builtin_bit_cast(float, u << 16);
}
__device__ __forceinline__ float bfhi(unsigned u) {
    return __builtin_bit_cast(float, u & 0xffff0000u);
}

// ---- stage A: range x slice LDS binning; ZERO global atomics ----
__global__ __launch_bounds__(256) void
k_poolscan(const int* __restrict__ cluster, const float* __restrict__ x,
           float4* __restrict__ partials, int N, int K, int R) {
    __shared__ float bins[CR * 4];       // 64 KB
    const int tid = threadIdx.x;
    const int r   = blockIdx.x % R;
    const int s   = blockIdx.x / R;
    const unsigned base = (unsigned)r * CR;

    for (int i = tid; i < CR * 4; i += 256) bins[i] = 0.f;
    __syncthreads();

    const int P4 = N >> 2;               // uint4 count
    const int Q  = P4 / NS;
    const int i1 = (s == NS - 1) ? P4 : (s + 1) * Q;
    const uint4* __restrict__ cl4 = reinterpret_cast<const uint4*>(cluster);

    int i = s * Q + tid;
    uint4 c = (i < i1) ? cl4[i] : make_uint4(~0u, ~0u, ~0u, ~0u);
    while (i < i1) {
        const int inext = i + 256;
        uint4 cn = (inext < i1) ? cl4[inext] : make_uint4(~0u, ~0u, ~0u, ~0u);

        const unsigned r0 = c.x - base, r1 = c.y - base, r2 = c.z - base, r3 = c.w - base;
        const bool m0 = r0 < CR, m1 = r1 < CR, m2 = r2 < CR, m3 = r3 < CR;
        const int n = i * 4;

        float a0=0.f,a1=0.f,a2=0.f, b0=0.f,b1=0.f,b2=0.f;
        float d0=0.f,d1=0.f,d2=0.f, e0=0.f,e1=0.f,e2=0.f;
        if (m0) { a0 = x[3*n+0];  a1 = x[3*n+1];  a2 = x[3*n+2]; }
        if (m1) { b0 = x[3*n+3];  b1 = x[3*n+4];  b2 = x[3*n+5]; }
        if (m2) { d0 = x[3*n+6];  d1 = x[3*n+7];  d2 = x[3*n+8]; }
        if (m3) { e0 = x[3*n+9];  e1 = x[3*n+10]; e2 = x[3*n+11]; }

        if (m0) { atomicAdd(&bins[r0*4+0], a0); atomicAdd(&bins[r0*4+1], a1);
                  atomicAdd(&bins[r0*4+2], a2); atomicAdd(&bins[r0*4+3], 1.f); }
        if (m1) { atomicAdd(&bins[r1*4+0], b0); atomicAdd(&bins[r1*4+1], b1);
                  atomicAdd(&bins[r1*4+2], b2); atomicAdd(&bins[r1*4+3], 1.f); }
        if (m2) { atomicAdd(&bins[r2*4+0], d0); atomicAdd(&bins[r2*4+1], d1);
                  atomicAdd(&bins[r2*4+2], d2); atomicAdd(&bins[r2*4+3], 1.f); }
        if (m3) { atomicAdd(&bins[r3*4+0], e0); atomicAdd(&bins[r3*4+1], e1);
                  atomicAdd(&bins[r3*4+2], e2); atomicAdd(&bins[r3*4+3], 1.f); }

        c = cn; i = inext;
    }
    if (s == NS - 1) {
        for (int n = P4 * 4 + tid; n < N; n += 256) {
            unsigned rr = (unsigned)cluster[n] - base;
            if (rr < CR) {
                atomicAdd(&bins[rr*4+0], x[3*n+0]);
                atomicAdd(&bins[rr*4+1], x[3*n+1]);
                atomicAdd(&bins[rr*4+2], x[3*n+2]);
                atomicAdd(&bins[rr*4+3], 1.f);
            }
        }
    }
    __syncthreads();

    float4* __restrict__ plane = partials + (size_t)s * K;
    for (int t = tid; t < CR; t += 256) {
        int k = (int)base + t;
        if (k < K)
            plane[k] = make_float4(bins[t*4+0], bins[t*4+1], bins[t*4+2], bins[t*4+3]);
    }
}

// ---- stage R: reduce NS planes -> pooled means; sentinel row at K ----
__global__ void k_reduce(const float4* __restrict__ partials, float4* __restrict__ pooled,
                         int K) {
    int k = blockIdx.x * blockDim.x + threadIdx.x;
    if (k < K) {
        float sx = 0.f, sy = 0.f, sz = 0.f, ct = 0.f;
        #pragma unroll
        for (int p = 0; p < NS; ++p) {
            float4 s = partials[(size_t)p * K + k];
            sx += s.x; sy += s.y; sz += s.z; ct += s.w;
        }
        float inv = 1.0f / fmaxf(ct, 1.0f);
        pooled[k] = make_float4(sx * inv, sy * inv, sz * inv, 0.f);
    } else if (k == K) {
        pooled[K] = make_float4(0.f, 0.f, 0.f, 0.f);
    }
}

// ---- stage B: fold W_conv @ W_lin[3:,:] -> bf16, pre-packed in MFMA B-fragment
// order. Wfold[kk][ch], kk = o*3+i (0..80, zero for 81..95), 3 k-steps of 32.
__global__ void k_fold(const float* __restrict__ Wc, const float* __restrict__ Wl,
                       unsigned short* __restrict__ Wpk) {
    int t = blockIdx.x * blockDim.x + threadIdx.x;
    if (t >= WPK_N) return;
    int j  = t & 7;
    int l  = (t >> 3) & 63;
    int st = t >> 9;
    int s  = st >> 2, tt = st & 3;
    int kk = 32 * s + 8 * (l >> 4) + j;
    int ch = 16 * tt + (l & 15);
    float acc = 0.f;
    if (kk < NB * IN_C) {
        #pragma unroll
        for (int j2 = 0; j2 < OUT_C; ++j2)
            acc = fmaf(Wc[kk * 64 + j2], Wl[(IN_C + j2) * OUT_C + ch], acc);
    }
    Wpk[t] = f2bf(acc);
}

// ---- stage C: MFMA conv -> bf16 v. Block = 64 clusters; wave = 16 cl x 64 ch. ----
__global__ __launch_bounds__(256) void
k_conv(const int* __restrict__ nb, const float4* __restrict__ pooled4,
       const unsigned short* __restrict__ Wpk, const float* __restrict__ b_lin,
       unsigned short* __restrict__ vbf, int K) {
    __shared__ float G[64][100];         // 25.6 KB; pad 100 -> <=2-way conflicts
    const int tid   = threadIdx.x;
    const int cbase = blockIdx.x * 64;

    {
        const int c = tid & 63;
        const int og = tid >> 6;                      // 0..3
        for (int kk = 81 + og; kk < 100; kk += 4) G[c][kk] = 0.f;  // zero A-pad
        const int kglob = min(cbase + c, K - 1);
        const int* nbrow = nb + (size_t)kglob * NB;
        for (int o = og; o < NB; o += 4) {
            unsigned s = min((unsigned)nbrow[o], (unsigned)K);  // -1 -> sentinel K
            float4 p = pooled4[s];
            G[c][3*o+0] = p.x; G[c][3*o+1] = p.y; G[c][3*o+2] = p.z;
        }
    }
    __syncthreads();

    const int lane = tid & 63;
    const int wv   = tid >> 6;           // wave -> clusters [wv*16, +16)
    const int m    = lane & 15;          // A row / D col
    const int b    = lane >> 4;          // k-block / D row group

    bf16x8 bw[12];
    const bf16x8* wp = reinterpret_cast<const bf16x8*>(Wpk);
    #pragma unroll
    for (int st = 0; st < 12; ++st) bw[st] = wp[st * 64 + lane];

    f32x4 acc[4];
    #pragma unroll
    for (int t = 0; t < 4; ++t) {
        float bb = b_lin[16 * t + m];
        acc[t] = (f32x4){bb, bb, bb, bb};
    }

    const float* grow = &G[wv * 16 + m][0];
    #pragma unroll
    for (int s = 0; s < 3; ++s) {
        float4 g0 = *reinterpret_cast<const float4*>(grow + 32 * s + 8 * b);
        float4 g1 = *reinterpret_cast<const float4*>(grow + 32 * s + 8 * b + 4);
        bf16x8 af;
        af[0] = (short)f2bf(g0.x); af[1] = (short)f2bf(g0.y);
        af[2] = (short)f2bf(g0.z); af[3] = (short)f2bf(g0.w);
        af[4] = (short)f2bf(g1.x); af[5] = (short)f2bf(g1.y);
        af[6] = (short)f2bf(g1.z); af[7] = (short)f2bf(g1.w);
        #pragma unroll
        for (int t = 0; t < 4; ++t)
            acc[t] = __builtin_amdgcn_mfma_f32_16x16x32_bf16(af, bw[s * 4 + t], acc[t], 0, 0, 0);
    }

    // D: col = lane&15, row = (lane>>4)*4 + reg
    #pragma unroll
    for (int t = 0; t < 4; ++t) {
        #pragma unroll
        for (int r = 0; r < 4; ++r) {
            int crow = cbase + wv * 16 + 4 * b + r;
            if (crow < K)
                vbf[(size_t)crow * OUT_C + 16 * t + m] = f2bf(acc[t][r]);
        }
    }
}

// ---- stage D: one-shot, 8 lanes/point. u = x @ W_lin[0:3] + v[cluster] ----
__global__ __launch_bounds__(256) void
k_point(const float* __restrict__ x, const int* __restrict__ cluster,
        const unsigned short* __restrict__ vbf, const float* __restrict__ Wl,
        float* __restrict__ out, int N) {
    const int tid = blockIdx.x * 256 + threadIdx.x;
    const int n   = tid >> 3;            // point
    const int jj  = (tid & 7) * 8;       // channel octet
    if (n >= N) return;

    const int c  = cluster[n];           // broadcast across 8 lanes
    const float x0 = x[n * 3 + 0];
    const float x1 = x[n * 3 + 1];
    const float x2 = x[n * 3 + 2];

    const float4 w0a = *reinterpret_cast<const float4*>(Wl + 0 * OUT_C + jj);
    const float4 w0b = *reinterpret_cast<const float4*>(Wl + 0 * OUT_C + jj + 4);
    const float4 w1a = *reinterpret_cast<const float4*>(Wl + 1 * OUT_C + jj);
    const float4 w1b = *reinterpret_cast<const float4*>(Wl + 1 * OUT_C + jj + 4);
    const float4 w2a = *reinterpret_cast<const float4*>(Wl + 2 * OUT_C + jj);
    const float4 w2b = *reinterpret_cast<const float4*>(Wl + 2 * OUT_C + jj + 4);

    const uint4 vr = *reinterpret_cast<const uint4*>(vbf + (size_t)c * OUT_C + jj);

    f32x4 oa, ob;
    oa[0] = fmaf(x0, w0a.x, fmaf(x1, w1a.x, fmaf(x2, w2a.x, bflo(vr.x))));
    oa[1] = fmaf(x0, w0a.y, fmaf(x1, w1a.y, fmaf(x2, w2a.y, bfhi(vr.x))));
    oa[2] = fmaf(x0, w0a.z, fmaf(x1, w1a.z, fmaf(x2, w2a.z, bflo(vr.y))));
    oa[3] = fmaf(x0, w0a.w, fmaf(x1, w1a.w, fmaf(x2, w2a.w, bfhi(vr.y))));
    ob[0] = fmaf(x0, w0b.x, fmaf(x1, w1b.x, fmaf(x2, w2b.x, bflo(vr.z))));
    ob[1] = fmaf(x0, w0b.y, fmaf(x1, w1b.y, fmaf(x2, w2b.y, bfhi(vr.z))));
    ob[2] = fmaf(x0, w0b.z, fmaf(x1, w1b.z, fmaf(x2, w2b.z, bflo(vr.w))));
    ob[3] = fmaf(x0, w0b.w, fmaf(x1, w1b.w, fmaf(x2, w2b.w, bfhi(vr.w))));

    float* op = out + (size_t)n * OUT_C + jj;
    __builtin_nontemporal_store(oa, reinterpret_cast<f32x4*>(op));
    __builtin_nontemporal_store(ob, reinterpret_cast<f32x4*>(op + 4));
}

extern "C" void kernel_launch(void* const* d_in, const int* in_sizes, int n_in,
                              void* d_out, int out_size, void* d_ws, size_t ws_size,
                              hipStream_t stream) {
    const float* x      = (const float*)d_in[0];
    const int*   cluster= (const int*)  d_in[1];
    const int*   nb     = (const int*)  d_in[2];
    const float* W_conv = (const float*)d_in[3];
    const float* W_lin  = (const float*)d_in[4];
    const float* b_lin  = (const float*)d_in[5];
    float* out = (float*)d_out;

    const int N = in_sizes[1];         // 1,000,000
    const int K = in_sizes[2] / NB;    // 200,000

    // workspace layout
    char* ws = (char*)d_ws;
    float4* pooled4 = (float4*)ws;                     // (K+1) * 16 B (sentinel at K)
    size_t off = (size_t)(K + 1) * sizeof(float4);
    off = ((off + 255) / 256) * 256;
    unsigned short* Wpk = (unsigned short*)(ws + off); // 12.3 KB packed bf16 weights
    off += ((WPK_N * sizeof(unsigned short) + 255) / 256) * 256;
    // big region: partials (NS*K*16B = 51.2 MB) and, after reduce consumes
    // them, vbf (K*64*2B = 25.6 MB) reuses the front of the same region.
    float4* partials = (float4*)(ws + off);
    unsigned short* vbf = (unsigned short*)(ws + off);

    k_fold <<<(WPK_N + 255) / 256, 256, 0, stream>>>(W_conv, W_lin, Wpk);

    const int R = (K + CR - 1) / CR;                   // 49 ranges
    k_poolscan<<<R * NS, 256, 0, stream>>>(cluster, x, partials, N, K, R);
    k_reduce<<<(K + 1 + 255) / 256, 256, 0, stream>>>(partials, pooled4, K);

    const int conv_blocks = (K + 63) / 64;             // 3125
    k_conv<<<conv_blocks, 256, 0, stream>>>(nb, pooled4, Wpk, b_lin, vbf, K);

    const int point_blocks = (N * 8 + 255) / 256;      // 31250
    k_point<<<point_blocks, 256, 0, stream>>>(x, cluster, vbf, W_lin, out, N);
}